// Round 3
// baseline (222.575 us; speedup 1.0000x reference)
//
#include <hip/hip_runtime.h>

constexpr int N_NODES = 100000;
constexpr int N_EDGES = 1600000;
constexpr int F = 128;
constexpr int H = 8;
constexpr float ALPHA = 0.2f;
constexpr float EPSF = 1e-12f;

constexpr int PSHIFT = 8;                         // 256 nodes per partition
constexpr int PN = 1 << PSHIFT;                   // 256
constexpr int NPART = (N_NODES + PN - 1) / PN;    // 391
constexpr int MAXPART = 5120;                     // mean 4096 + ~16 sigma
constexpr int EPB = 4096;                         // edges per block in pass A
constexpr int OCAP = 4096;                        // overflow list capacity
constexpr int NPAIR = H / 2;                      // 4 head-pairs

// K1: per-node scores; aa staged in LDS (broadcast reads, conflict-free).
// Writes: srn[n*16+0..7]=s_src (kB staging + fallback), sd[n*8+h]=s_dst
// (kB gathers + fallback), sd2[pi*N+n]=float2 s_dst pair-plane (k4p gathers).
__global__ void k1_scores(const float* __restrict__ x, const float* __restrict__ aa,
                          float* __restrict__ srn, float* __restrict__ sd,
                          float2* __restrict__ sd2) {
    __shared__ float sa[H * 2 * F];
    for (int i = threadIdx.x; i < H * 2 * F; i += blockDim.x) sa[i] = aa[i];
    __syncthreads();
    int node = blockIdx.x * blockDim.x + threadIdx.x;
    if (node >= N_NODES) return;
    const float4* xr = reinterpret_cast<const float4*>(x + (size_t)node * F);
    float accs[H], accd[H];
#pragma unroll
    for (int h = 0; h < H; ++h) { accs[h] = 0.f; accd[h] = 0.f; }
    for (int f4 = 0; f4 < F / 4; ++f4) {
        float4 xv = xr[f4];
#pragma unroll
        for (int h = 0; h < H; ++h) {
            float4 av = *reinterpret_cast<const float4*>(&sa[h * 2 * F + 4 * f4]);
            float4 bv = *reinterpret_cast<const float4*>(&sa[h * 2 * F + F + 4 * f4]);
            accs[h] += xv.x * av.x + xv.y * av.y + xv.z * av.z + xv.w * av.w;
            accd[h] += xv.x * bv.x + xv.y * bv.y + xv.z * bv.z + xv.w * bv.w;
        }
    }
    float4* os = reinterpret_cast<float4*>(srn + (size_t)node * 16);
    os[0] = make_float4(accs[0], accs[1], accs[2], accs[3]);
    os[1] = make_float4(accs[4], accs[5], accs[6], accs[7]);
    float4* od = reinterpret_cast<float4*>(sd + (size_t)node * H);
    od[0] = make_float4(accd[0], accd[1], accd[2], accd[3]);
    od[1] = make_float4(accd[4], accd[5], accd[6], accd[7]);
#pragma unroll
    for (int pi = 0; pi < NPAIR; ++pi)
        sd2[(size_t)pi * N_NODES + node] = make_float2(accd[2 * pi], accd[2 * pi + 1]);
}

// Pass A: radix-partition edges by row>>8. 1024 thr/block. One global atomic
// per (block,partition). Payload u32 = (row&255)<<17 | col  (col < 2^17).
__global__ void __launch_bounds__(1024)
kA_part(const int* __restrict__ row, const int* __restrict__ col,
        int* __restrict__ gcnt, unsigned* __restrict__ part,
        int* __restrict__ ocnt, int2* __restrict__ olist) {
    __shared__ int hist[NPART];
    __shared__ int base[NPART];
    const int t = threadIdx.x;
    const int e0 = blockIdx.x * EPB;
    for (int p = t; p < NPART; p += 1024) hist[p] = 0;
    __syncthreads();
    for (int k = 0; k < EPB / 1024; ++k) {
        int i = e0 + k * 1024 + t;
        if (i < N_EDGES) atomicAdd(&hist[row[i] >> PSHIFT], 1);
    }
    __syncthreads();
    for (int p = t; p < NPART; p += 1024) {
        int h = hist[p];
        base[p] = h ? atomicAdd(&gcnt[p], h) : 0;
        hist[p] = 0;  // reuse as cursor
    }
    __syncthreads();
    for (int k = 0; k < EPB / 1024; ++k) {
        int i = e0 + k * 1024 + t;
        if (i < N_EDGES) {
            int r = row[i], c = col[i];
            int p = r >> PSHIFT;
            int slot = base[p] + atomicAdd(&hist[p], 1);
            unsigned pk = ((unsigned)(r & (PN - 1)) << 17) | (unsigned)c;
            if (slot < MAXPART) {
                part[(size_t)p * MAXPART + slot] = pk;
            } else {
                int q = atomicAdd(ocnt, 1);
                if (q < OCAP) olist[q] = make_int2(p, (int)pk);
            }
        }
    }
}

// Pass B: atomic-free counting-sort reduce (R2 win). Step-4 remapped to one
// (node, head-pair) item per thread (PN*NPAIR == 1024 == blockDim): each
// thread walks its node's segment once accumulating TWO heads (halves
// sorted_c broadcasts; 4 lanes/edge read one coalesced 32B sd segment).
// Writes spn[pi*N+node] = {s0, s1, rinv0, rinv1} for k4p.
__global__ void __launch_bounds__(1024)
kB_sum(const float* __restrict__ sd, const unsigned* __restrict__ part,
       const int* __restrict__ gcnt, const int* __restrict__ ocnt,
       const int2* __restrict__ olist, const float* __restrict__ srn,
       float4* __restrict__ spn) {
    __shared__ unsigned plist[MAXPART];     // 20 KB
    __shared__ unsigned sorted_c[MAXPART];  // 20 KB
    __shared__ int hist[PN];
    __shared__ int off[PN + 1];
    __shared__ int cur[PN];
    __shared__ float ssrc[PN * H];          // 8 KB
    const int p = blockIdx.x;
    const int t = threadIdx.x;
    const int nbase = p << PSHIFT;

    for (int i = t; i < PN; i += 1024) hist[i] = 0;
    for (int j = t; j < PN * H; j += 1024) {
        int n = nbase + (j >> 3);
        ssrc[j] = (n < N_NODES) ? srn[(size_t)n * 16 + (j & 7)] : 0.f;
    }
    __syncthreads();

    int cnt = gcnt[p]; if (cnt > MAXPART) cnt = MAXPART;
    const unsigned* pp = part + (size_t)p * MAXPART;

    // 1. stage + histogram
    for (int i = t; i < cnt; i += 1024) {
        unsigned pk = pp[i];
        plist[i] = pk;
        atomicAdd(&hist[pk >> 17], 1);
    }
    __syncthreads();

    // 2. inclusive Hillis-Steele scan over 256 counters
    for (int d = 1; d < PN; d <<= 1) {
        int add = 0;
        if (t >= d && t < PN) add = hist[t - d];
        __syncthreads();
        if (t < PN) hist[t] += add;
        __syncthreads();
    }
    if (t < PN) off[t + 1] = hist[t];
    if (t == 0) off[0] = 0;
    __syncthreads();
    if (t < PN) cur[t] = off[t];
    __syncthreads();

    // 3. scatter col into segment-sorted order
    for (int i = t; i < cnt; i += 1024) {
        unsigned pk = plist[i];
        int rl = (int)(pk >> 17);
        int slot = atomicAdd(&cur[rl], 1);
        sorted_c[slot] = pk & 0x1FFFFu;
    }
    __syncthreads();

    // 4. register-accumulate per (node, pair); no atomics
    int mo = *ocnt; if (mo > OCAP) mo = OCAP;
    {
        int nl = t >> 2, pi = t & 3;        // PN*NPAIR == 1024 exactly
        int node = nbase + nl;
        int k0 = off[nl], k1e = off[nl + 1];
        float s0 = ssrc[nl * 8 + 2 * pi];
        float s1 = ssrc[nl * 8 + 2 * pi + 1];
        float a0 = 0.f, a1 = 0.f;
        for (int k = k0; k < k1e; ++k) {
            int c = (int)sorted_c[k];       // LDS broadcast across 4 lanes
            float2 d = *reinterpret_cast<const float2*>(&sd[(size_t)c * H + 2 * pi]);
            float e0 = s0 + d.x; e0 = e0 > 0.f ? e0 : ALPHA * e0;
            float e1 = s1 + d.y; e1 = e1 > 0.f ? e1 : ALPHA * e1;
            a0 += __expf(e0); a1 += __expf(e1);
        }
        for (int j = 0; j < mo; ++j) {      // overflow edges (expected: none)
            int2 oe = olist[j];
            if (oe.x == p && (int)(((unsigned)oe.y) >> 17) == nl) {
                int c = oe.y & 0x1FFFF;
                float2 d = *reinterpret_cast<const float2*>(&sd[(size_t)c * H + 2 * pi]);
                float e0 = s0 + d.x; e0 = e0 > 0.f ? e0 : ALPHA * e0;
                float e1 = s1 + d.y; e1 = e1 > 0.f ? e1 : ALPHA * e1;
                a0 += __expf(e0); a1 += __expf(e1);
            }
        }
        if (node < N_NODES)
            spn[(size_t)pi * N_NODES + node] =
                make_float4(s0, s1, 1.f / (a0 + EPSF), 1.f / (a1 + EPSF));
    }
}

// K4p: head-pair planes. grid=(chunks, 4 pairs); blockIdx.x-fastest dispatch
// gives temporal phase separation so each pass's hot tables (spn plane 1.6MB
// + sd2 plane 0.8MB = 2.4MB) fit per-XCD L2 (4MB) -> gathers become L2 hits.
// Identical f32 arithmetic to old k4 (bitwise-same outputs).
__global__ void k4p(const int* __restrict__ row, const int* __restrict__ col,
                    const float4* __restrict__ spn, const float2* __restrict__ sd2,
                    float* __restrict__ out) {
    int i = blockIdx.x * blockDim.x + threadIdx.x;
    if (i >= N_EDGES) return;
    int pi = blockIdx.y;
    int r = row[i], c = col[i];
    float4 q = spn[(size_t)pi * N_NODES + r];   // {s0, s1, rinv0, rinv1}
    float2 d = sd2[(size_t)pi * N_NODES + c];
    float e0 = q.x + d.x; e0 = e0 > 0.f ? e0 : ALPHA * e0;
    float e1 = q.y + d.y; e1 = e1 > 0.f ? e1 : ALPHA * e1;
    out[(size_t)(2 * pi) * N_EDGES + i]     = __expf(e0) * q.z;
    out[(size_t)(2 * pi + 1) * N_EDGES + i] = __expf(e1) * q.w;
}

// ---------------- atomic fallback (tiny ws) ----------------
__global__ void kz_zero_sums(float* __restrict__ srn) {
    int t = blockIdx.x * blockDim.x + threadIdx.x;
    if (t >= N_NODES * H) return;
    srn[(size_t)(t >> 3) * 16 + 8 + (t & 7)] = 0.f;
}

__global__ void k3nm_sum(const float* __restrict__ srn_ro, const float* __restrict__ s_dst,
                         const int* __restrict__ row, const int* __restrict__ col,
                         float* __restrict__ srn) {
    int i = blockIdx.x * blockDim.x + threadIdx.x;
    if (i >= N_EDGES) return;
    int r = row[i], c = col[i];
    const float4* sr = reinterpret_cast<const float4*>(srn_ro + (size_t)r * 16);
    float4 a0 = sr[0], a1 = sr[1];
    const float4* sc = reinterpret_cast<const float4*>(s_dst + (size_t)c * H);
    float4 b0 = sc[0], b1 = sc[1];
    float ev[H] = {a0.x + b0.x, a0.y + b0.y, a0.z + b0.z, a0.w + b0.w,
                   a1.x + b1.x, a1.y + b1.y, a1.z + b1.z, a1.w + b1.w};
#pragma unroll
    for (int h = 0; h < H; ++h) {
        float e = ev[h] > 0.f ? ev[h] : ALPHA * ev[h];
        atomicAdd(&srn[(size_t)r * 16 + 8 + h], __expf(e));
    }
}

__global__ void k_inv(float* __restrict__ srn) {
    int t = blockIdx.x * blockDim.x + threadIdx.x;
    if (t >= N_NODES * H) return;
    int n = t >> 3, h = t & 7;
    float s = srn[(size_t)n * 16 + 8 + h];
    srn[(size_t)n * 16 + 8 + h] = 1.0f / (s + EPSF);
}

__global__ void k4_out(const int* __restrict__ row, const int* __restrict__ col,
                       const float* __restrict__ srn, const float* __restrict__ s_dst,
                       float* __restrict__ out) {
    int i = blockIdx.x * blockDim.x + threadIdx.x;
    if (i >= N_EDGES) return;
    int r = row[i], c = col[i];
    const float4* sr = reinterpret_cast<const float4*>(srn + (size_t)r * 16);
    float4 a0 = sr[0], a1 = sr[1], r0 = sr[2], r1 = sr[3];
    const float4* sc = reinterpret_cast<const float4*>(s_dst + (size_t)c * H);
    float4 b0 = sc[0], b1 = sc[1];
    float ev[H] = {a0.x + b0.x, a0.y + b0.y, a0.z + b0.z, a0.w + b0.w,
                   a1.x + b1.x, a1.y + b1.y, a1.z + b1.z, a1.w + b1.w};
    float rv[H] = {r0.x, r0.y, r0.z, r0.w, r1.x, r1.y, r1.z, r1.w};
#pragma unroll
    for (int h = 0; h < H; ++h) {
        float e = ev[h] > 0.f ? ev[h] : ALPHA * ev[h];
        out[(size_t)h * N_EDGES + i] = __expf(e) * rv[h];
    }
}

extern "C" void kernel_launch(void* const* d_in, const int* in_sizes, int n_in,
                              void* d_out, int out_size, void* d_ws, size_t ws_size,
                              hipStream_t stream) {
    const float* x   = (const float*)d_in[0];
    const int*   row = (const int*)d_in[1];
    const int*   col = (const int*)d_in[2];
    const float* aa  = (const float*)d_in[3];
    float* out = (float*)d_out;

    // ws layout: srn [N][16] | sd [N][8] | spn [4][N] f4 | sd2 [4][N] f2
    //            | part | gcnt | ocnt(16) | olist
    float*    srn  = (float*)d_ws;
    float*    sd   = srn + (size_t)N_NODES * 16;
    float4*   spn  = (float4*)(sd + (size_t)N_NODES * H);
    float2*   sd2  = (float2*)(spn + (size_t)NPAIR * N_NODES);
    unsigned* part = (unsigned*)(sd2 + (size_t)NPAIR * N_NODES);
    int*      gcnt = (int*)(part + (size_t)NPART * MAXPART);
    int*      ocnt = gcnt + NPART;
    int2*     olist = (int2*)(ocnt + 16);

    const size_t need_full = ((size_t)N_NODES * (16 + 8 + 16 + 8) + (size_t)NPART * MAXPART
                              + NPART + 16 + 2 * OCAP) * 4;  // ~27.3 MB
    const size_t need_min  = (size_t)N_NODES * (16 + 8) * 4;  // fallback: srn + sd

    const int B = 256;
    const int GE = (N_EDGES + B - 1) / B;
    const int GN = (N_NODES + B - 1) / B;

    k1_scores<<<GN, B, 0, stream>>>(x, aa, srn, sd, sd2);

    if (ws_size >= need_full) {
        hipMemsetAsync(gcnt, 0, (size_t)(NPART + 16) * sizeof(int), stream);
        kA_part<<<(N_EDGES + EPB - 1) / EPB, 1024, 0, stream>>>(row, col, gcnt, part, ocnt, olist);
        kB_sum<<<NPART, 1024, 0, stream>>>(sd, part, gcnt, ocnt, olist, srn, spn);
        dim3 g4(GE, NPAIR);
        k4p<<<g4, B, 0, stream>>>(row, col, spn, sd2, out);
    } else if (ws_size >= need_min) {
        kz_zero_sums<<<(N_NODES * H + B - 1) / B, B, 0, stream>>>(srn);
        k3nm_sum<<<GE, B, 0, stream>>>(srn, sd, row, col, srn);
        k_inv<<<(N_NODES * H + B - 1) / B, B, 0, stream>>>(srn);
        k4_out<<<GE, B, 0, stream>>>(row, col, srn, sd, out);
    }
}

// Round 4
// 214.673 us; speedup vs baseline: 1.0368x; 1.0368x over previous
//
#include <hip/hip_runtime.h>

constexpr int N_NODES = 100000;
constexpr int N_EDGES = 1600000;
constexpr int F = 128;
constexpr int H = 8;
constexpr float ALPHA = 0.2f;
constexpr float EPSF = 1e-12f;

constexpr int PSHIFT = 8;                         // 256 nodes per partition
constexpr int PN = 1 << PSHIFT;                   // 256
constexpr int NPART = (N_NODES + PN - 1) / PN;    // 391
constexpr int MAXPART = 5120;                     // mean 4096 + ~16 sigma
constexpr int EPB = 4096;                         // edges per block in pass A
constexpr int OCAP = 4096;                        // overflow list capacity

// K1: per-node scores; aa staged in LDS (broadcast reads, conflict-free).
// srn[n*16+0..7]=s_src, srn[n*16+8..15]=rinv (filled by kB); sd[n*8+h]=s_dst.
__global__ void k1_scores(const float* __restrict__ x, const float* __restrict__ aa,
                          float* __restrict__ srn, float* __restrict__ sd) {
    __shared__ float sa[H * 2 * F];
    for (int i = threadIdx.x; i < H * 2 * F; i += blockDim.x) sa[i] = aa[i];
    __syncthreads();
    int node = blockIdx.x * blockDim.x + threadIdx.x;
    if (node >= N_NODES) return;
    const float4* xr = reinterpret_cast<const float4*>(x + (size_t)node * F);
    float accs[H], accd[H];
#pragma unroll
    for (int h = 0; h < H; ++h) { accs[h] = 0.f; accd[h] = 0.f; }
    for (int f4 = 0; f4 < F / 4; ++f4) {
        float4 xv = xr[f4];
#pragma unroll
        for (int h = 0; h < H; ++h) {
            float4 av = *reinterpret_cast<const float4*>(&sa[h * 2 * F + 4 * f4]);
            float4 bv = *reinterpret_cast<const float4*>(&sa[h * 2 * F + F + 4 * f4]);
            accs[h] += xv.x * av.x + xv.y * av.y + xv.z * av.z + xv.w * av.w;
            accd[h] += xv.x * bv.x + xv.y * bv.y + xv.z * bv.z + xv.w * bv.w;
        }
    }
    float4* os = reinterpret_cast<float4*>(srn + (size_t)node * 16);
    os[0] = make_float4(accs[0], accs[1], accs[2], accs[3]);
    os[1] = make_float4(accs[4], accs[5], accs[6], accs[7]);
    float4* od = reinterpret_cast<float4*>(sd + (size_t)node * H);
    od[0] = make_float4(accd[0], accd[1], accd[2], accd[3]);
    od[1] = make_float4(accd[4], accd[5], accd[6], accd[7]);
}

// Pass A: radix-partition edges by row>>8. 1024 thr/block. One global atomic
// per (block,partition). Payload u32 = (row&255)<<17 | col  (col < 2^17).
__global__ void __launch_bounds__(1024)
kA_part(const int* __restrict__ row, const int* __restrict__ col,
        int* __restrict__ gcnt, unsigned* __restrict__ part,
        int* __restrict__ ocnt, int2* __restrict__ olist) {
    __shared__ int hist[NPART];
    __shared__ int base[NPART];
    const int t = threadIdx.x;
    const int e0 = blockIdx.x * EPB;
    for (int p = t; p < NPART; p += 1024) hist[p] = 0;
    __syncthreads();
    for (int k = 0; k < EPB / 1024; ++k) {
        int i = e0 + k * 1024 + t;
        if (i < N_EDGES) atomicAdd(&hist[row[i] >> PSHIFT], 1);
    }
    __syncthreads();
    for (int p = t; p < NPART; p += 1024) {
        int h = hist[p];
        base[p] = h ? atomicAdd(&gcnt[p], h) : 0;
        hist[p] = 0;  // reuse as cursor
    }
    __syncthreads();
    for (int k = 0; k < EPB / 1024; ++k) {
        int i = e0 + k * 1024 + t;
        if (i < N_EDGES) {
            int r = row[i], c = col[i];
            int p = r >> PSHIFT;
            int slot = base[p] + atomicAdd(&hist[p], 1);
            unsigned pk = ((unsigned)(r & (PN - 1)) << 17) | (unsigned)c;
            if (slot < MAXPART) {
                part[(size_t)p * MAXPART + slot] = pk;
            } else {
                int q = atomicAdd(ocnt, 1);
                if (q < OCAP) olist[q] = make_int2(p, (int)pk);
            }
        }
    }
}

// Pass B: atomic-free counting-sort reduce. Step 4: one (node, head-pair)
// item per thread (PN*NPAIR==1024); segment walk UNROLLED x4 — batch 4 LDS
// col reads then 4 independent sd gathers (was a serial LDS->global dependent
// chain, mean 16 iters). 4 pair-lanes of a node issue adjacent float2 -> one
// coalesced 32B transaction per edge. rinv written to srn[n*16+8..15].
__global__ void __launch_bounds__(1024)
kB_sum(const float* __restrict__ sd, const unsigned* __restrict__ part,
       const int* __restrict__ gcnt, const int* __restrict__ ocnt,
       const int2* __restrict__ olist, float* __restrict__ srn) {
    __shared__ unsigned plist[MAXPART];     // 20 KB
    __shared__ unsigned sorted_c[MAXPART];  // 20 KB
    __shared__ int hist[PN];
    __shared__ int off[PN + 1];
    __shared__ int cur[PN];
    __shared__ float ssrc[PN * H];          // 8 KB
    const int p = blockIdx.x;
    const int t = threadIdx.x;
    const int nbase = p << PSHIFT;

    for (int i = t; i < PN; i += 1024) hist[i] = 0;
    for (int j = t; j < PN * H; j += 1024) {
        int n = nbase + (j >> 3);
        ssrc[j] = (n < N_NODES) ? srn[(size_t)n * 16 + (j & 7)] : 0.f;
    }
    __syncthreads();

    int cnt = gcnt[p]; if (cnt > MAXPART) cnt = MAXPART;
    const unsigned* pp = part + (size_t)p * MAXPART;

    // 1. stage + histogram
    for (int i = t; i < cnt; i += 1024) {
        unsigned pk = pp[i];
        plist[i] = pk;
        atomicAdd(&hist[pk >> 17], 1);
    }
    __syncthreads();

    // 2. inclusive Hillis-Steele scan over 256 counters
    for (int d = 1; d < PN; d <<= 1) {
        int add = 0;
        if (t >= d && t < PN) add = hist[t - d];
        __syncthreads();
        if (t < PN) hist[t] += add;
        __syncthreads();
    }
    if (t < PN) off[t + 1] = hist[t];
    if (t == 0) off[0] = 0;
    __syncthreads();
    if (t < PN) cur[t] = off[t];
    __syncthreads();

    // 3. scatter col into segment-sorted order
    for (int i = t; i < cnt; i += 1024) {
        unsigned pk = plist[i];
        int rl = (int)(pk >> 17);
        int slot = atomicAdd(&cur[rl], 1);
        sorted_c[slot] = pk & 0x1FFFFu;
    }
    __syncthreads();

    // 4. register-accumulate per (node, pair), unrolled x4; no atomics
    int mo = *ocnt; if (mo > OCAP) mo = OCAP;
    {
        int nl = t >> 2, pi = t & 3;
        int node = nbase + nl;
        int k0 = off[nl], k1e = off[nl + 1];
        float s0 = ssrc[nl * 8 + 2 * pi];
        float s1 = ssrc[nl * 8 + 2 * pi + 1];
        float a0 = 0.f, a1 = 0.f;
        int k = k0;
        for (; k + 4 <= k1e; k += 4) {
            int c0 = (int)sorted_c[k],     c1 = (int)sorted_c[k + 1];
            int c2 = (int)sorted_c[k + 2], c3 = (int)sorted_c[k + 3];
            float2 d0 = *reinterpret_cast<const float2*>(&sd[(size_t)c0 * H + 2 * pi]);
            float2 d1 = *reinterpret_cast<const float2*>(&sd[(size_t)c1 * H + 2 * pi]);
            float2 d2 = *reinterpret_cast<const float2*>(&sd[(size_t)c2 * H + 2 * pi]);
            float2 d3 = *reinterpret_cast<const float2*>(&sd[(size_t)c3 * H + 2 * pi]);
            float e;
            e = s0 + d0.x; e = e > 0.f ? e : ALPHA * e; a0 += __expf(e);
            e = s1 + d0.y; e = e > 0.f ? e : ALPHA * e; a1 += __expf(e);
            e = s0 + d1.x; e = e > 0.f ? e : ALPHA * e; a0 += __expf(e);
            e = s1 + d1.y; e = e > 0.f ? e : ALPHA * e; a1 += __expf(e);
            e = s0 + d2.x; e = e > 0.f ? e : ALPHA * e; a0 += __expf(e);
            e = s1 + d2.y; e = e > 0.f ? e : ALPHA * e; a1 += __expf(e);
            e = s0 + d3.x; e = e > 0.f ? e : ALPHA * e; a0 += __expf(e);
            e = s1 + d3.y; e = e > 0.f ? e : ALPHA * e; a1 += __expf(e);
        }
        for (; k < k1e; ++k) {
            int c = (int)sorted_c[k];
            float2 d = *reinterpret_cast<const float2*>(&sd[(size_t)c * H + 2 * pi]);
            float e0 = s0 + d.x; e0 = e0 > 0.f ? e0 : ALPHA * e0;
            float e1 = s1 + d.y; e1 = e1 > 0.f ? e1 : ALPHA * e1;
            a0 += __expf(e0); a1 += __expf(e1);
        }
        for (int j = 0; j < mo; ++j) {      // overflow edges (expected: none)
            int2 oe = olist[j];
            if (oe.x == p && (int)(((unsigned)oe.y) >> 17) == nl) {
                int c = oe.y & 0x1FFFF;
                float2 d = *reinterpret_cast<const float2*>(&sd[(size_t)c * H + 2 * pi]);
                float e0 = s0 + d.x; e0 = e0 > 0.f ? e0 : ALPHA * e0;
                float e1 = s1 + d.y; e1 = e1 > 0.f ? e1 : ALPHA * e1;
                a0 += __expf(e0); a1 += __expf(e1);
            }
        }
        if (node < N_NODES) {
            srn[(size_t)node * 16 + 8 + 2 * pi]     = 1.f / (a0 + EPSF);
            srn[(size_t)node * 16 + 8 + 2 * pi + 1] = 1.f / (a1 + EPSF);
        }
    }
}

// K4 v3: 64B-row layout (request-optimal) + 2 edges per thread. 12 independent
// 16B gathers + 2 int2 idx loads per thread -> 2x outstanding-request capacity
// vs R2 (k4 is gather-MLP bound, proven by R3's k4p regression). Stores pack
// the 2 adjacent edges as float2 per head plane (coalesced).
__global__ void __launch_bounds__(256)
k4_out(const int* __restrict__ row, const int* __restrict__ col,
       const float* __restrict__ srn, const float* __restrict__ sd,
       float* __restrict__ out) {
    int i0 = (blockIdx.x * blockDim.x + threadIdx.x) * 2;
    if (i0 >= N_EDGES) return;
    int2 rr = *reinterpret_cast<const int2*>(&row[i0]);
    int2 cc = *reinterpret_cast<const int2*>(&col[i0]);
    const float4* srA = reinterpret_cast<const float4*>(srn + (size_t)rr.x * 16);
    const float4* srB = reinterpret_cast<const float4*>(srn + (size_t)rr.y * 16);
    const float4* scA = reinterpret_cast<const float4*>(sd + (size_t)cc.x * H);
    const float4* scB = reinterpret_cast<const float4*>(sd + (size_t)cc.y * H);
    float4 sA0 = srA[0], sA1 = srA[1], rA0 = srA[2], rA1 = srA[3];
    float4 sB0 = srB[0], sB1 = srB[1], rB0 = srB[2], rB1 = srB[3];
    float4 dA0 = scA[0], dA1 = scA[1];
    float4 dB0 = scB[0], dB1 = scB[1];
    float eA[H] = {sA0.x + dA0.x, sA0.y + dA0.y, sA0.z + dA0.z, sA0.w + dA0.w,
                   sA1.x + dA1.x, sA1.y + dA1.y, sA1.z + dA1.z, sA1.w + dA1.w};
    float eB[H] = {sB0.x + dB0.x, sB0.y + dB0.y, sB0.z + dB0.z, sB0.w + dB0.w,
                   sB1.x + dB1.x, sB1.y + dB1.y, sB1.z + dB1.z, sB1.w + dB1.w};
    float vA[H] = {rA0.x, rA0.y, rA0.z, rA0.w, rA1.x, rA1.y, rA1.z, rA1.w};
    float vB[H] = {rB0.x, rB0.y, rB0.z, rB0.w, rB1.x, rB1.y, rB1.z, rB1.w};
#pragma unroll
    for (int h = 0; h < H; ++h) {
        float a = eA[h] > 0.f ? eA[h] : ALPHA * eA[h];
        float b = eB[h] > 0.f ? eB[h] : ALPHA * eB[h];
        float2 o = make_float2(__expf(a) * vA[h], __expf(b) * vB[h]);
        *reinterpret_cast<float2*>(&out[(size_t)h * N_EDGES + i0]) = o;
    }
}

// ---------------- atomic fallback (tiny ws) ----------------
__global__ void kz_zero_sums(float* __restrict__ srn) {
    int t = blockIdx.x * blockDim.x + threadIdx.x;
    if (t >= N_NODES * H) return;
    srn[(size_t)(t >> 3) * 16 + 8 + (t & 7)] = 0.f;
}

__global__ void k3nm_sum(const float* __restrict__ srn_ro, const float* __restrict__ s_dst,
                         const int* __restrict__ row, const int* __restrict__ col,
                         float* __restrict__ srn) {
    int i = blockIdx.x * blockDim.x + threadIdx.x;
    if (i >= N_EDGES) return;
    int r = row[i], c = col[i];
    const float4* sr = reinterpret_cast<const float4*>(srn_ro + (size_t)r * 16);
    float4 a0 = sr[0], a1 = sr[1];
    const float4* sc = reinterpret_cast<const float4*>(s_dst + (size_t)c * H);
    float4 b0 = sc[0], b1 = sc[1];
    float ev[H] = {a0.x + b0.x, a0.y + b0.y, a0.z + b0.z, a0.w + b0.w,
                   a1.x + b1.x, a1.y + b1.y, a1.z + b1.z, a1.w + b1.w};
#pragma unroll
    for (int h = 0; h < H; ++h) {
        float e = ev[h] > 0.f ? ev[h] : ALPHA * ev[h];
        atomicAdd(&srn[(size_t)r * 16 + 8 + h], __expf(e));
    }
}

__global__ void k_inv(float* __restrict__ srn) {
    int t = blockIdx.x * blockDim.x + threadIdx.x;
    if (t >= N_NODES * H) return;
    int n = t >> 3, h = t & 7;
    float s = srn[(size_t)n * 16 + 8 + h];
    srn[(size_t)n * 16 + 8 + h] = 1.0f / (s + EPSF);
}

extern "C" void kernel_launch(void* const* d_in, const int* in_sizes, int n_in,
                              void* d_out, int out_size, void* d_ws, size_t ws_size,
                              hipStream_t stream) {
    const float* x   = (const float*)d_in[0];
    const int*   row = (const int*)d_in[1];
    const int*   col = (const int*)d_in[2];
    const float* aa  = (const float*)d_in[3];
    float* out = (float*)d_out;

    // ws layout: srn [N][16] | sd [N][8] | part | gcnt | ocnt(16) | olist
    float*    srn  = (float*)d_ws;
    float*    sd   = srn + (size_t)N_NODES * 16;
    unsigned* part = (unsigned*)(sd + (size_t)N_NODES * H);
    int*      gcnt = (int*)(part + (size_t)NPART * MAXPART);
    int*      ocnt = gcnt + NPART;
    int2*     olist = (int2*)(ocnt + 16);

    const size_t need_b = ((size_t)N_NODES * 24 + (size_t)NPART * MAXPART
                           + NPART + 16 + 2 * OCAP) * 4;  // ~17.7 MB

    const int B = 256;
    const int GE  = (N_EDGES + B - 1) / B;
    const int GE2 = (N_EDGES + 2 * B - 1) / (2 * B);
    const int GN  = (N_NODES + B - 1) / B;

    k1_scores<<<GN, B, 0, stream>>>(x, aa, srn, sd);

    if (ws_size >= need_b) {
        hipMemsetAsync(gcnt, 0, (size_t)(NPART + 16) * sizeof(int), stream);
        kA_part<<<(N_EDGES + EPB - 1) / EPB, 1024, 0, stream>>>(row, col, gcnt, part, ocnt, olist);
        kB_sum<<<NPART, 1024, 0, stream>>>(sd, part, gcnt, ocnt, olist, srn);
    } else {
        kz_zero_sums<<<(N_NODES * H + B - 1) / B, B, 0, stream>>>(srn);
        k3nm_sum<<<GE, B, 0, stream>>>(srn, sd, row, col, srn);
        k_inv<<<(N_NODES * H + B - 1) / B, B, 0, stream>>>(srn);
    }

    k4_out<<<GE2, B, 0, stream>>>(row, col, srn, sd, out);
}

// Round 5
// 205.800 us; speedup vs baseline: 1.0815x; 1.0431x over previous
//
#include <hip/hip_runtime.h>

constexpr int N_NODES = 100000;
constexpr int N_EDGES = 1600000;
constexpr int F = 128;
constexpr int H = 8;
constexpr float ALPHA = 0.2f;
constexpr float EPSF = 1e-12f;

constexpr int PSHIFT = 8;                         // 256 nodes per partition
constexpr int PN = 1 << PSHIFT;                   // 256
constexpr int NPART = (N_NODES + PN - 1) / PN;    // 391
constexpr int MAXPART = 5120;                     // mean 4096 + ~16 sigma
constexpr int EPB = 4096;                         // edges per block in pass A
constexpr int OCAP = 4096;                        // overflow list capacity

static_assert(N_EDGES % 64 == 0, "k4_hs assumes 64-edge blocks");

// K1: per-node scores; aa staged in LDS (broadcast reads, conflict-free).
// srn[n*16+0..7]=s_src, srn[n*16+8..15]=rinv (filled by kB); sd[n*8+h]=s_dst.
__global__ void k1_scores(const float* __restrict__ x, const float* __restrict__ aa,
                          float* __restrict__ srn, float* __restrict__ sd) {
    __shared__ float sa[H * 2 * F];
    for (int i = threadIdx.x; i < H * 2 * F; i += blockDim.x) sa[i] = aa[i];
    __syncthreads();
    int node = blockIdx.x * blockDim.x + threadIdx.x;
    if (node >= N_NODES) return;
    const float4* xr = reinterpret_cast<const float4*>(x + (size_t)node * F);
    float accs[H], accd[H];
#pragma unroll
    for (int h = 0; h < H; ++h) { accs[h] = 0.f; accd[h] = 0.f; }
    for (int f4 = 0; f4 < F / 4; ++f4) {
        float4 xv = xr[f4];
#pragma unroll
        for (int h = 0; h < H; ++h) {
            float4 av = *reinterpret_cast<const float4*>(&sa[h * 2 * F + 4 * f4]);
            float4 bv = *reinterpret_cast<const float4*>(&sa[h * 2 * F + F + 4 * f4]);
            accs[h] += xv.x * av.x + xv.y * av.y + xv.z * av.z + xv.w * av.w;
            accd[h] += xv.x * bv.x + xv.y * bv.y + xv.z * bv.z + xv.w * bv.w;
        }
    }
    float4* os = reinterpret_cast<float4*>(srn + (size_t)node * 16);
    os[0] = make_float4(accs[0], accs[1], accs[2], accs[3]);
    os[1] = make_float4(accs[4], accs[5], accs[6], accs[7]);
    float4* od = reinterpret_cast<float4*>(sd + (size_t)node * H);
    od[0] = make_float4(accd[0], accd[1], accd[2], accd[3]);
    od[1] = make_float4(accd[4], accd[5], accd[6], accd[7]);
}

// Pass A: radix-partition edges by row>>8. 1024 thr/block. One global atomic
// per (block,partition). Payload u32 = (row&255)<<17 | col  (col < 2^17).
// R5: r/c staged in registers across the barrier (kills 12.8 MB re-read).
__global__ void __launch_bounds__(1024)
kA_part(const int* __restrict__ row, const int* __restrict__ col,
        int* __restrict__ gcnt, unsigned* __restrict__ part,
        int* __restrict__ ocnt, int2* __restrict__ olist) {
    __shared__ int hist[NPART];
    __shared__ int base[NPART];
    const int t = threadIdx.x;
    const int e0 = blockIdx.x * EPB;
    constexpr int K = EPB / 1024;
    int rr[K], cc[K];
    for (int p = t; p < NPART; p += 1024) hist[p] = 0;
    __syncthreads();
#pragma unroll
    for (int k = 0; k < K; ++k) {
        int i = e0 + k * 1024 + t;
        if (i < N_EDGES) {
            rr[k] = row[i];
            cc[k] = col[i];
            atomicAdd(&hist[rr[k] >> PSHIFT], 1);
        } else rr[k] = -1;
    }
    __syncthreads();
    for (int p = t; p < NPART; p += 1024) {
        int h = hist[p];
        base[p] = h ? atomicAdd(&gcnt[p], h) : 0;
        hist[p] = 0;  // reuse as cursor
    }
    __syncthreads();
#pragma unroll
    for (int k = 0; k < K; ++k) {
        if (rr[k] >= 0) {
            int r = rr[k], c = cc[k];
            int p = r >> PSHIFT;
            int slot = base[p] + atomicAdd(&hist[p], 1);
            unsigned pk = ((unsigned)(r & (PN - 1)) << 17) | (unsigned)c;
            if (slot < MAXPART) {
                part[(size_t)p * MAXPART + slot] = pk;
            } else {
                int q = atomicAdd(ocnt, 1);
                if (q < OCAP) olist[q] = make_int2(p, (int)pk);
            }
        }
    }
}

// Pass B: atomic-free counting-sort reduce (unchanged from R4).
__global__ void __launch_bounds__(1024)
kB_sum(const float* __restrict__ sd, const unsigned* __restrict__ part,
       const int* __restrict__ gcnt, const int* __restrict__ ocnt,
       const int2* __restrict__ olist, float* __restrict__ srn) {
    __shared__ unsigned plist[MAXPART];     // 20 KB
    __shared__ unsigned sorted_c[MAXPART];  // 20 KB
    __shared__ int hist[PN];
    __shared__ int off[PN + 1];
    __shared__ int cur[PN];
    __shared__ float ssrc[PN * H];          // 8 KB
    const int p = blockIdx.x;
    const int t = threadIdx.x;
    const int nbase = p << PSHIFT;

    for (int i = t; i < PN; i += 1024) hist[i] = 0;
    for (int j = t; j < PN * H; j += 1024) {
        int n = nbase + (j >> 3);
        ssrc[j] = (n < N_NODES) ? srn[(size_t)n * 16 + (j & 7)] : 0.f;
    }
    __syncthreads();

    int cnt = gcnt[p]; if (cnt > MAXPART) cnt = MAXPART;
    const unsigned* pp = part + (size_t)p * MAXPART;

    for (int i = t; i < cnt; i += 1024) {
        unsigned pk = pp[i];
        plist[i] = pk;
        atomicAdd(&hist[pk >> 17], 1);
    }
    __syncthreads();

    for (int d = 1; d < PN; d <<= 1) {
        int add = 0;
        if (t >= d && t < PN) add = hist[t - d];
        __syncthreads();
        if (t < PN) hist[t] += add;
        __syncthreads();
    }
    if (t < PN) off[t + 1] = hist[t];
    if (t == 0) off[0] = 0;
    __syncthreads();
    if (t < PN) cur[t] = off[t];
    __syncthreads();

    for (int i = t; i < cnt; i += 1024) {
        unsigned pk = plist[i];
        int rl = (int)(pk >> 17);
        int slot = atomicAdd(&cur[rl], 1);
        sorted_c[slot] = pk & 0x1FFFFu;
    }
    __syncthreads();

    int mo = *ocnt; if (mo > OCAP) mo = OCAP;
    {
        int nl = t >> 2, pi = t & 3;
        int node = nbase + nl;
        int k0 = off[nl], k1e = off[nl + 1];
        float s0 = ssrc[nl * 8 + 2 * pi];
        float s1 = ssrc[nl * 8 + 2 * pi + 1];
        float a0 = 0.f, a1 = 0.f;
        int k = k0;
        for (; k + 4 <= k1e; k += 4) {
            int c0 = (int)sorted_c[k],     c1 = (int)sorted_c[k + 1];
            int c2 = (int)sorted_c[k + 2], c3 = (int)sorted_c[k + 3];
            float2 d0 = *reinterpret_cast<const float2*>(&sd[(size_t)c0 * H + 2 * pi]);
            float2 d1 = *reinterpret_cast<const float2*>(&sd[(size_t)c1 * H + 2 * pi]);
            float2 d2 = *reinterpret_cast<const float2*>(&sd[(size_t)c2 * H + 2 * pi]);
            float2 d3 = *reinterpret_cast<const float2*>(&sd[(size_t)c3 * H + 2 * pi]);
            float e;
            e = s0 + d0.x; e = e > 0.f ? e : ALPHA * e; a0 += __expf(e);
            e = s1 + d0.y; e = e > 0.f ? e : ALPHA * e; a1 += __expf(e);
            e = s0 + d1.x; e = e > 0.f ? e : ALPHA * e; a0 += __expf(e);
            e = s1 + d1.y; e = e > 0.f ? e : ALPHA * e; a1 += __expf(e);
            e = s0 + d2.x; e = e > 0.f ? e : ALPHA * e; a0 += __expf(e);
            e = s1 + d2.y; e = e > 0.f ? e : ALPHA * e; a1 += __expf(e);
            e = s0 + d3.x; e = e > 0.f ? e : ALPHA * e; a0 += __expf(e);
            e = s1 + d3.y; e = e > 0.f ? e : ALPHA * e; a1 += __expf(e);
        }
        for (; k < k1e; ++k) {
            int c = (int)sorted_c[k];
            float2 d = *reinterpret_cast<const float2*>(&sd[(size_t)c * H + 2 * pi]);
            float e0 = s0 + d.x; e0 = e0 > 0.f ? e0 : ALPHA * e0;
            float e1 = s1 + d.y; e1 = e1 > 0.f ? e1 : ALPHA * e1;
            a0 += __expf(e0); a1 += __expf(e1);
        }
        for (int j = 0; j < mo; ++j) {      // overflow edges (expected: none)
            int2 oe = olist[j];
            if (oe.x == p && (int)(((unsigned)oe.y) >> 17) == nl) {
                int c = oe.y & 0x1FFFF;
                float2 d = *reinterpret_cast<const float2*>(&sd[(size_t)c * H + 2 * pi]);
                float e0 = s0 + d.x; e0 = e0 > 0.f ? e0 : ALPHA * e0;
                float e1 = s1 + d.y; e1 = e1 > 0.f ? e1 : ALPHA * e1;
                a0 += __expf(e0); a1 += __expf(e1);
            }
        }
        if (node < N_NODES) {
            srn[(size_t)node * 16 + 8 + 2 * pi]     = 1.f / (a0 + EPSF);
            srn[(size_t)node * 16 + 8 + 2 * pi + 1] = 1.f / (a1 + EPSF);
        }
    }
}

// K4 head-split: 8 lanes per edge, lane h owns head h. Each gather instruction
// now touches 8 contiguous 32B segments (8 lanes x 4B consecutive) instead of
// 64 scattered addresses -> ~8x fewer TA lane-requests; cache-line footprint
// IDENTICAL to R2/R4 (discriminator: request-issue vs fill-BW bound).
// Results staged in LDS (stride-72: max 2-way = free) and stored coalesced
// (256B per wave per plane).
__global__ void __launch_bounds__(512)
k4_hs(const int* __restrict__ row, const int* __restrict__ col,
      const float* __restrict__ srn, const float* __restrict__ sd,
      float* __restrict__ out) {
    __shared__ int ridx[64], cidx[64];
    __shared__ float sm[8][72];
    const int e0 = blockIdx.x * 64;
    const int t = threadIdx.x;
    if (t < 64) ridx[t] = row[e0 + t];
    else if (t < 128) cidx[t - 64] = col[e0 + t - 64];
    __syncthreads();
    {
        int el = t >> 3, h = t & 7;
        int r = ridx[el], c = cidx[el];
        float s  = srn[(size_t)r * 16 + h];       // 8 lanes -> one 32B segment
        float rv = srn[(size_t)r * 16 + 8 + h];   // adjacent 32B (same line)
        float d  = sd[(size_t)c * H + h];         // one 32B segment
        float e = s + d;
        e = e > 0.f ? e : ALPHA * e;
        sm[h][el] = __expf(e) * rv;
    }
    __syncthreads();
    {
        int h2 = t >> 6, j = t & 63;              // 512 thr = 8 planes x 64
        out[(size_t)h2 * N_EDGES + e0 + j] = sm[h2][j];
    }
}

// ---------------- atomic fallback (tiny ws) ----------------
__global__ void kz_zero_sums(float* __restrict__ srn) {
    int t = blockIdx.x * blockDim.x + threadIdx.x;
    if (t >= N_NODES * H) return;
    srn[(size_t)(t >> 3) * 16 + 8 + (t & 7)] = 0.f;
}

__global__ void k3nm_sum(const float* __restrict__ srn_ro, const float* __restrict__ s_dst,
                         const int* __restrict__ row, const int* __restrict__ col,
                         float* __restrict__ srn) {
    int i = blockIdx.x * blockDim.x + threadIdx.x;
    if (i >= N_EDGES) return;
    int r = row[i], c = col[i];
    const float4* sr = reinterpret_cast<const float4*>(srn_ro + (size_t)r * 16);
    float4 a0 = sr[0], a1 = sr[1];
    const float4* sc = reinterpret_cast<const float4*>(s_dst + (size_t)c * H);
    float4 b0 = sc[0], b1 = sc[1];
    float ev[H] = {a0.x + b0.x, a0.y + b0.y, a0.z + b0.z, a0.w + b0.w,
                   a1.x + b1.x, a1.y + b1.y, a1.z + b1.z, a1.w + b1.w};
#pragma unroll
    for (int h = 0; h < H; ++h) {
        float e = ev[h] > 0.f ? ev[h] : ALPHA * ev[h];
        atomicAdd(&srn[(size_t)r * 16 + 8 + h], __expf(e));
    }
}

__global__ void k_inv(float* __restrict__ srn) {
    int t = blockIdx.x * blockDim.x + threadIdx.x;
    if (t >= N_NODES * H) return;
    int n = t >> 3, h = t & 7;
    float s = srn[(size_t)n * 16 + 8 + h];
    srn[(size_t)n * 16 + 8 + h] = 1.0f / (s + EPSF);
}

__global__ void k4_out(const int* __restrict__ row, const int* __restrict__ col,
                       const float* __restrict__ srn, const float* __restrict__ s_dst,
                       float* __restrict__ out) {
    int i = blockIdx.x * blockDim.x + threadIdx.x;
    if (i >= N_EDGES) return;
    int r = row[i], c = col[i];
    const float4* sr = reinterpret_cast<const float4*>(srn + (size_t)r * 16);
    float4 a0 = sr[0], a1 = sr[1], r0 = sr[2], r1 = sr[3];
    const float4* sc = reinterpret_cast<const float4*>(s_dst + (size_t)c * H);
    float4 b0 = sc[0], b1 = sc[1];
    float ev[H] = {a0.x + b0.x, a0.y + b0.y, a0.z + b0.z, a0.w + b0.w,
                   a1.x + b1.x, a1.y + b1.y, a1.z + b1.z, a1.w + b1.w};
    float rv[H] = {r0.x, r0.y, r0.z, r0.w, r1.x, r1.y, r1.z, r1.w};
#pragma unroll
    for (int h = 0; h < H; ++h) {
        float e = ev[h] > 0.f ? ev[h] : ALPHA * ev[h];
        out[(size_t)h * N_EDGES + i] = __expf(e) * rv[h];
    }
}

extern "C" void kernel_launch(void* const* d_in, const int* in_sizes, int n_in,
                              void* d_out, int out_size, void* d_ws, size_t ws_size,
                              hipStream_t stream) {
    const float* x   = (const float*)d_in[0];
    const int*   row = (const int*)d_in[1];
    const int*   col = (const int*)d_in[2];
    const float* aa  = (const float*)d_in[3];
    float* out = (float*)d_out;

    // ws layout: srn [N][16] | sd [N][8] | part | gcnt | ocnt(16) | olist
    float*    srn  = (float*)d_ws;
    float*    sd   = srn + (size_t)N_NODES * 16;
    unsigned* part = (unsigned*)(sd + (size_t)N_NODES * H);
    int*      gcnt = (int*)(part + (size_t)NPART * MAXPART);
    int*      ocnt = gcnt + NPART;
    int2*     olist = (int2*)(ocnt + 16);

    const size_t need_b = ((size_t)N_NODES * 24 + (size_t)NPART * MAXPART
                           + NPART + 16 + 2 * OCAP) * 4;  // ~17.7 MB

    const int B = 256;
    const int GE  = (N_EDGES + B - 1) / B;
    const int GN  = (N_NODES + B - 1) / B;

    k1_scores<<<GN, B, 0, stream>>>(x, aa, srn, sd);

    if (ws_size >= need_b) {
        hipMemsetAsync(gcnt, 0, (size_t)(NPART + 16) * sizeof(int), stream);
        kA_part<<<(N_EDGES + EPB - 1) / EPB, 1024, 0, stream>>>(row, col, gcnt, part, ocnt, olist);
        kB_sum<<<NPART, 1024, 0, stream>>>(sd, part, gcnt, ocnt, olist, srn);
        k4_hs<<<N_EDGES / 64, 512, 0, stream>>>(row, col, srn, sd, out);
    } else {
        kz_zero_sums<<<(N_NODES * H + B - 1) / B, B, 0, stream>>>(srn);
        k3nm_sum<<<GE, B, 0, stream>>>(srn, sd, row, col, srn);
        k_inv<<<(N_NODES * H + B - 1) / B, B, 0, stream>>>(srn);
        k4_out<<<GE, B, 0, stream>>>(row, col, srn, sd, out);
    }
}